// Round 4
// baseline (109.435 us; speedup 1.0000x reference)
//
#include <hip/hip_runtime.h>
#include <stdint.h>

using ushort8 = __attribute__((ext_vector_type(8))) unsigned short;
using bf16x8  = __attribute__((ext_vector_type(8))) __bf16;
using f32x16  = __attribute__((ext_vector_type(16))) float;

#define AS1 __attribute__((address_space(1)))
#define AS3 __attribute__((address_space(3)))

__device__ __forceinline__ unsigned short f2bf(float x){
  uint32_t u = __builtin_bit_cast(uint32_t, x);
  u = (u + 0x7FFFu + ((u >> 16) & 1u)) >> 16;   // RNE
  return (unsigned short)u;
}
__device__ __forceinline__ float bf2f(unsigned short b){
  uint32_t u = ((uint32_t)b) << 16;
  return __builtin_bit_cast(float, u);
}

__device__ __forceinline__ f32x16 mfma16(bf16x8 a, bf16x8 b, f32x16 c){
  return __builtin_amdgcn_mfma_f32_32x32x16_bf16(a, b, c, 0, 0, 0);
}

__device__ __forceinline__ bf16x8 cvt8(const float* p){
  ushort8 v;
  #pragma unroll
  for (int j = 0; j < 8; ++j) v[j] = f2bf(p[j]);
  return __builtin_bit_cast(bf16x8, v);
}

// Pre-pass: Wb2[s][pt][ch][r][w][8] bf16 with the bank-swizzle PERMUTATION
// BAKED INTO THE DATA: slot (r,w) holds c-chunk (w ^ (r&7)). Staging then uses
// LINEAR per-lane addresses (lane*16) and the LDS image equals the swizzled
// layout the a-frag reads expect (identical to round-3's verified image).
// s<128: A[p][c] = W[(s*128+p)*128+c]; s=128: A[p][i] = b[i*128+p].
__global__ void prep_wb2(const float* __restrict__ W, const float* __restrict__ bias,
                         unsigned short* __restrict__ Wb2){
  int e = blockIdx.x * 256 + threadIdx.x;
  if (e >= 129 * 16384) return;
  int jj = e & 7, w = (e >> 3) & 7, r = (e >> 6) & 31;
  int ch = (e >> 11) & 1, pt = (e >> 12) & 3, s = e >> 14;
  int p = pt * 32 + r;
  int c = ch * 64 + ((w ^ (r & 7)) << 3) + jj;
  float v = (s < 128) ? W[(s << 14) + (p << 7) + c] : bias[(c << 7) + p];
  Wb2[e] = f2bf(v);
}

// dynmlp: grid 256. XCD-aware mapping: h = (b>>2)&1 (so each XCD handles one
// K-half -> caches only 2.1MB of Wb2), tt = ((b>>3)<<2)|(b&3), phase = b>>3
// (step-order stagger: co-XCD WGs read different step blocks -> no L2 hotspot).
// 512 thr = 8 waves = 4 pt x 2 ch. Wave: 32p x 128t (F=4) x 64c.
// Private 4-buffer ring per wave (16KB), prefetch depth 3, counted vmcnt,
// NO barriers in the 64-step loop.  LDS: 128KB rings + 16KB imgT = 144KB.
__global__ __launch_bounds__(512, 2)
void dynmlp(const float* __restrict__ img, const float* __restrict__ loc,
            const unsigned short* __restrict__ Wb2, float* __restrict__ part){
  __shared__ __align__(16) char smem[147456];
  unsigned short* imgT = (unsigned short*)(smem + 131072);  // [64 s][128 t] u16
  float* ldsY = (float*)smem;                               // epilogue reuse

  const int b = blockIdx.x;
  const int h     = (b >> 2) & 1;
  const int tt    = ((b >> 3) << 2) | (b & 3);
  const int phase = b >> 3;                                 // 0..31
  const int tid = threadIdx.x, lane = tid & 63, wv = tid >> 6;
  const int pt = wv >> 1, ch = wv & 1;
  const int l31 = lane & 31, lg = lane >> 5;
  const int t0 = tt * 128;

  char* ringb = smem + wv * 16384;
  const char* sliceBase = (const char*)Wb2 +
      ((size_t)(h * 64) * 8 + (size_t)(pt * 2 + ch)) * 4096 + (lane << 4);
  const char* biasSrc = (const char*)Wb2 +
      ((size_t)128 * 8 + (size_t)(pt * 2 + ch)) * 4096 + (lane << 4);

  auto stg = [&](int psLocal, char* ldst){
    const char* g = sliceBase + (size_t)psLocal * 32768;
    char* l = ldst + (lane << 4);
    #pragma unroll
    for (int j = 0; j < 4; ++j)
      __builtin_amdgcn_global_load_lds((const AS1 uint32_t*)(g + j * 1024),
                                       (AS3 uint32_t*)(l + j * 1024), 16, 0, 0);
  };
  auto stgB = [&](char* ldst){
    char* l = ldst + (lane << 4);
    #pragma unroll
    for (int j = 0; j < 4; ++j)
      __builtin_amdgcn_global_load_lds((const AS1 uint32_t*)(biasSrc + j * 1024),
                                       (AS3 uint32_t*)(l + j * 1024), 16, 0, 0);
  };
  #define LP(k) (((k) + phase) & 63)

  // ---- prologue: depth-3 prefetch, imgT fill, register-stationary B-frags ----
  stg(LP(0), ringb);
  stg(LP(1), ringb + 4096);
  stg(LP(2), ringb + 8192);

  for (int e = tid; e < 2048; e += 512){
    int tl = e >> 4, iq = e & 15;
    float4 v = *(const float4*)&img[(size_t)(t0 + tl) * 128 + h * 64 + iq * 4];
    int a = iq * 4 * 128 + tl;
    imgT[a]       = f2bf(v.x);
    imgT[a + 128] = f2bf(v.y);
    imgT[a + 256] = f2bf(v.z);
    imgT[a + 384] = f2bf(v.w);
  }

  bf16x8 bfr[4][4];
  #pragma unroll
  for (int f = 0; f < 4; ++f){
    int t = t0 + f * 32 + l31;
    #pragma unroll
    for (int cc = 0; cc < 4; ++cc)
      bfr[f][cc] = cvt8(&loc[(size_t)t * 128 + ch * 64 + cc * 16 + lg * 8]);
  }

  int aoff[4];
  #pragma unroll
  for (int cc = 0; cc < 4; ++cc)
    aoff[cc] = (l31 * 8 + ((cc * 2 + lg) ^ (l31 & 7))) * 16;

  __syncthreads();   // imgT ready (only pre-epilogue barrier)

  f32x16 acc[4] = {{}, {}, {}, {}};

  auto cstep = [&](const char* bufp, int ps){
    const unsigned short* ir = imgT + ps * 128 + l31;
    float s0 = bf2f(ir[0]), s1 = bf2f(ir[32]), s2 = bf2f(ir[64]), s3 = bf2f(ir[96]);
    f32x16 S0 = {}, S1 = {}, S2 = {}, S3 = {};
    __builtin_amdgcn_s_setprio(1);
    #pragma unroll
    for (int cc = 0; cc < 4; ++cc){
      bf16x8 a = *(const bf16x8*)(bufp + aoff[cc]);
      S0 = mfma16(a, bfr[0][cc], S0);
      S1 = mfma16(a, bfr[1][cc], S1);
      S2 = mfma16(a, bfr[2][cc], S2);
      S3 = mfma16(a, bfr[3][cc], S3);
    }
    __builtin_amdgcn_s_setprio(0);
    acc[0] += S0 * s0; acc[1] += S1 * s1; acc[2] += S2 * s2; acc[3] += S3 * s3;
  };

  // ---- main loop: logical ki 0..59, buf = ki&3 (literal), prefetch ki+3 ----
  for (int kb = 0; kb < 60; kb += 4){
    #define BODY(J, PB) \
      stg(LP(kb + (J) + 3), ringb + (PB) * 4096); \
      asm volatile("s_waitcnt vmcnt(12)" ::: "memory"); \
      cstep(ringb + (J) * 4096, LP(kb + (J)));
    BODY(0, 3) BODY(1, 0) BODY(2, 1) BODY(3, 2)
    #undef BODY
  }
  // ---- tail: logical 60..63 (+ bias for h==0) ----
  stg(LP(63), ringb + 3 * 4096);
  asm volatile("s_waitcnt vmcnt(12)" ::: "memory");
  cstep(ringb, LP(60));
  if (h == 0){
    stgB(ringb);                                   // bias -> buf 0 (consumed)
    asm volatile("s_waitcnt vmcnt(12)" ::: "memory");
  } else {
    asm volatile("s_waitcnt vmcnt(8)" ::: "memory");
  }
  cstep(ringb + 4096, LP(61));
  if (h == 0) asm volatile("s_waitcnt vmcnt(8)" ::: "memory");
  else        asm volatile("s_waitcnt vmcnt(4)" ::: "memory");
  cstep(ringb + 8192, LP(62));
  if (h == 0) asm volatile("s_waitcnt vmcnt(4)" ::: "memory");
  else        asm volatile("s_waitcnt vmcnt(0)" ::: "memory");
  cstep(ringb + 12288, LP(63));
  if (h == 0){
    asm volatile("s_waitcnt vmcnt(0)" ::: "memory");
    const char* bufp = ringb;
    #pragma unroll
    for (int cc = 0; cc < 4; ++cc){
      bf16x8 a = *(const bf16x8*)(bufp + aoff[cc]);
      #pragma unroll
      for (int f = 0; f < 4; ++f){
        bf16x8 bi = cvt8(&img[(size_t)(t0 + f * 32 + l31) * 128 + ch * 64 + cc * 16 + lg * 8]);
        acc[f] = mfma16(a, bi, acc[f]);
      }
    }
  }

  // ---- epilogue: combine c-halves in LDS, write partial coalesced ----
  __syncthreads();
  if (ch == 0){
    #pragma unroll
    for (int f = 0; f < 4; ++f){
      int t_l = f * 32 + l31;
      #pragma unroll
      for (int r = 0; r < 16; ++r){
        int p = pt * 32 + (r & 3) + 8 * (r >> 2) + 4 * lg;
        ldsY[t_l * 129 + p] = acc[f][r];
      }
    }
  }
  __syncthreads();
  if (ch == 1){
    #pragma unroll
    for (int f = 0; f < 4; ++f){
      int t_l = f * 32 + l31;
      #pragma unroll
      for (int r = 0; r < 16; ++r){
        int p = pt * 32 + (r & 3) + 8 * (r >> 2) + 4 * lg;
        ldsY[t_l * 129 + p] += acc[f][r];
      }
    }
  }
  __syncthreads();
  float* dst = part + ((size_t)h * 16384 + t0) * 128;
  #pragma unroll
  for (int k = 0; k < 8; ++k){
    int idx4 = k * 512 + tid;
    int t_l = idx4 >> 5, q = idx4 & 31;
    const float* s = &ldsY[t_l * 129 + q * 4];
    float4 v = {s[0], s[1], s[2], s[3]};
    *(float4*)&dst[t_l * 128 + q * 4] = v;
  }
}

// LN kernel: y = part0 + part1, LayerNorm + ReLU. grid 256 x 512 thr.
__global__ __launch_bounds__(512)
void lnk(const float* __restrict__ part, const float* __restrict__ gamma,
         const float* __restrict__ beta, float* __restrict__ out){
  const int tid = threadIdx.x, lane = tid & 63, wv = tid >> 6;
  const float* p0 = part;
  const float* p1 = part + (size_t)16384 * 128;
  float g0  = gamma[lane], g1 = gamma[lane + 64];
  float be0 = beta[lane],  be1 = beta[lane + 64];
  int tb = blockIdx.x * 64 + wv * 8;
  #pragma unroll 1
  for (int k = 0; k < 8; ++k){
    size_t t = tb + k;
    float y0 = p0[t * 128 + lane]      + p1[t * 128 + lane];
    float y1 = p0[t * 128 + 64 + lane] + p1[t * 128 + 64 + lane];
    float s = y0 + y1, sq = y0 * y0 + y1 * y1;
    #pragma unroll
    for (int m = 32; m >= 1; m >>= 1){
      s  += __shfl_xor(s, m, 64);
      sq += __shfl_xor(sq, m, 64);
    }
    float mean = s * (1.0f / 128.0f);
    float var  = sq * (1.0f / 128.0f) - mean * mean;
    float rs   = rsqrtf(var + 1e-5f);
    float o0 = fmaxf((y0 - mean) * rs * g0 + be0, 0.0f);
    float o1 = fmaxf((y1 - mean) * rs * g1 + be1, 0.0f);
    out[t * 128 + lane]      = o0;
    out[t * 128 + 64 + lane] = o1;
  }
}

extern "C" void kernel_launch(void* const* d_in, const int* in_sizes, int n_in,
                              void* d_out, int out_size, void* d_ws, size_t ws_size,
                              hipStream_t stream){
  const float* img   = (const float*)d_in[0];
  const float* loc   = (const float*)d_in[1];
  const float* W     = (const float*)d_in[2];
  const float* bias  = (const float*)d_in[3];
  const float* gamma = (const float*)d_in[4];
  const float* beta  = (const float*)d_in[5];
  float* out = (float*)d_out;
  unsigned short* Wb2 = (unsigned short*)d_ws;                 // 4,227,072 B
  float* part = (float*)((char*)d_ws + 4227072);               // 2 x 16384 x 128 f32 = 16 MB

  prep_wb2<<<8256, 256, 0, stream>>>(W, bias, Wb2);
  dynmlp<<<256, 512, 0, stream>>>(img, loc, Wb2, part);
  lnk<<<256, 512, 0, stream>>>(part, gamma, beta, out);
}

// Round 6
// 109.287 us; speedup vs baseline: 1.0014x; 1.0014x over previous
//
#include <hip/hip_runtime.h>
#include <stdint.h>

using ushort8 = __attribute__((ext_vector_type(8))) unsigned short;
using bf16x8  = __attribute__((ext_vector_type(8))) __bf16;
using f32x16  = __attribute__((ext_vector_type(16))) float;
using f32x2   = __attribute__((ext_vector_type(2))) float;
using u32x4   = __attribute__((ext_vector_type(4))) uint32_t;
using us4     = __attribute__((ext_vector_type(4))) unsigned short;

__device__ __forceinline__ unsigned short f2bf(float x){
  uint32_t u = __builtin_bit_cast(uint32_t, x);
  u = (u + 0x7FFFu + ((u >> 16) & 1u)) >> 16;   // RNE
  return (unsigned short)u;
}
__device__ __forceinline__ float bf2f(unsigned short b){
  uint32_t u = ((uint32_t)b) << 16;
  return __builtin_bit_cast(float, u);
}

__device__ __forceinline__ f32x16 mfma16(bf16x8 a, bf16x8 b, f32x16 c){
  return __builtin_amdgcn_mfma_f32_32x32x16_bf16(a, b, c, 0, 0, 0);
}

__device__ __forceinline__ bf16x8 cvt8(const float* p){
  ushort8 v;
  #pragma unroll
  for (int j = 0; j < 8; ++j) v[j] = f2bf(p[j]);
  return __builtin_bit_cast(bf16x8, v);
}

// Pre-pass: Wb3[s][pt][ch][r 0..31][chunk 0..7][8 bf16], PLAIN fragment order.
// Slice (pt,ch) row r chunk w holds c = ch*64 + w*8 + j of step image s.
// s<128: A[p][c] = W[(s*128+p)*128+c] (p = pt*32+r); s=128: A[p][i] = b[i*128+p].
__global__ void prep_wb3(const float* __restrict__ W, const float* __restrict__ bias,
                         unsigned short* __restrict__ Wb3){
  int e = blockIdx.x * 256 + threadIdx.x;
  if (e >= 129 * 16384) return;
  int jj = e & 7, w = (e >> 3) & 7, r = (e >> 6) & 31;
  int ch = (e >> 11) & 1, pt = (e >> 12) & 3, s = e >> 14;
  int p = pt * 32 + r;
  int c = ch * 64 + w * 8 + jj;
  float v = (s < 128) ? W[(s << 14) + (p << 7) + c] : bias[(c << 7) + p];
  Wb3[e] = f2bf(v);
}

// dynmlp: grid 256 = 128 token-tiles x 2 K-halves (tt=b>>1, h=b&1 -> each XCD
// serves one fixed h, 2.1MB L2 footprint, lockstep step sharing like r3).
// 512 thr = 8 waves = 4 pt x 2 ch; wave tile 32p x 128t (F=4) x 64c.
// NO LDS staging of W: A-fragments loaded global->register (private per wave),
// double-banked avA/avB at distance-1, no asm waits, no loop barriers.
// FRAGMENT LAYOUT (r5 bugfix): lane (l31,lg) needs k-chunk (cc*2 + lg) of its
// row -> load g[i*2 + lg], NOT g[i*2].
// LDS: imgT 16KB (union with 66KB ldsY used only in epilogue).
__global__ __launch_bounds__(512, 2)
void dynmlp(const float* __restrict__ img, const float* __restrict__ loc,
            const unsigned short* __restrict__ Wb3, float* __restrict__ part){
  __shared__ __align__(16) char smem[66048];
  unsigned short* imgT = (unsigned short*)smem;   // [64 s][slot(t)] u16, 16KB
  float* ldsY = (float*)smem;                     // [128 t][129 p] f32 (epilogue)

  const int b = blockIdx.x;
  const int tt = b >> 1, h = b & 1;
  const int tid = threadIdx.x, lane = tid & 63, wv = tid >> 6;
  const int pt = wv >> 1, ch = wv & 1;
  const int l31 = lane & 31, lg = lane >> 5;
  const int t0 = tt * 128;

  // per-lane slice base: slice(pt,ch) + row l31
  const char* wslice = (const char*)Wb3 +
      ((size_t)(h * 64) * 8 + (size_t)(pt * 2 + ch)) * 4096 + l31 * 128;
  const char* biasSl = (const char*)Wb3 +
      ((size_t)128 * 8 + (size_t)(pt * 2 + ch)) * 4096 + l31 * 128;

  // ---- imgT fill: slot(t) = (t&31)*4 + (t>>5); row s = i - h*64 ----
  for (int e = tid; e < 2048; e += 512){
    int tl = e & 127, iq = e >> 7;
    float4 v = *(const float4*)&img[(size_t)(t0 + tl) * 128 + h * 64 + iq * 4];
    int slot = (tl & 31) * 4 + (tl >> 5);
    imgT[(iq * 4 + 0) * 128 + slot] = f2bf(v.x);
    imgT[(iq * 4 + 1) * 128 + slot] = f2bf(v.y);
    imgT[(iq * 4 + 2) * 128 + slot] = f2bf(v.z);
    imgT[(iq * 4 + 3) * 128 + slot] = f2bf(v.w);
  }

  // ---- register-stationary B-frags (loc, this wave's c-half) ----
  bf16x8 bfr[4][4];
  #pragma unroll
  for (int f = 0; f < 4; ++f){
    int t = t0 + f * 32 + l31;
    #pragma unroll
    for (int cc = 0; cc < 4; ++cc)
      bfr[f][cc] = cvt8(&loc[(size_t)t * 128 + ch * 64 + cc * 16 + lg * 8]);
  }

  // persistent zero C-operand (asm-pinned so it is materialized ONCE)
  f32x16 Z;
  #pragma unroll
  for (int i = 0; i < 16; ++i) Z[i] = 0.0f;
  asm volatile("" : "+v"(Z));

  // acc as 4 x 8 f32-pairs (pk_fma targets); never feeds MFMA
  f32x2 accp[4][8];
  #pragma unroll
  for (int f = 0; f < 4; ++f)
    #pragma unroll
    for (int q = 0; q < 8; ++q) accp[f][q] = (f32x2){0.0f, 0.0f};

  // prologue load: step 0 fragments (k-chunk = i*2 + lg  <- r5 bugfix)
  u32x4 avA[4], avB[4];
  {
    const u32x4* g = (const u32x4*)wslice;
    #pragma unroll
    for (int i = 0; i < 4; ++i) avA[i] = g[i * 2 + lg];
  }
  const char* gp = wslice + 32768;     // next step source

  __syncthreads();                     // imgT ready

  const unsigned short* imgP = imgT + l31 * 4;

  // one step: MFMA chains (C=Z, D fresh) then pk_fma tail with img scalars
  #define STEPBODY(AV, W4) do { \
    bf16x8 a0 = __builtin_bit_cast(bf16x8, AV[0]); \
    bf16x8 a1 = __builtin_bit_cast(bf16x8, AV[1]); \
    bf16x8 a2 = __builtin_bit_cast(bf16x8, AV[2]); \
    bf16x8 a3 = __builtin_bit_cast(bf16x8, AV[3]); \
    __builtin_amdgcn_s_setprio(1); \
    f32x16 T0 = mfma16(a0, bfr[0][0], Z); \
    f32x16 T1 = mfma16(a0, bfr[1][0], Z); \
    f32x16 T2 = mfma16(a0, bfr[2][0], Z); \
    f32x16 T3 = mfma16(a0, bfr[3][0], Z); \
    T0 = mfma16(a1, bfr[0][1], T0); T1 = mfma16(a1, bfr[1][1], T1); \
    T2 = mfma16(a1, bfr[2][1], T2); T3 = mfma16(a1, bfr[3][1], T3); \
    T0 = mfma16(a2, bfr[0][2], T0); T1 = mfma16(a2, bfr[1][2], T1); \
    T2 = mfma16(a2, bfr[2][2], T2); T3 = mfma16(a2, bfr[3][2], T3); \
    T0 = mfma16(a3, bfr[0][3], T0); T1 = mfma16(a3, bfr[1][3], T1); \
    T2 = mfma16(a3, bfr[2][3], T2); T3 = mfma16(a3, bfr[3][3], T3); \
    __builtin_amdgcn_s_setprio(0); \
    float s0 = bf2f(W4[0]), s1 = bf2f(W4[1]), s2 = bf2f(W4[2]), s3 = bf2f(W4[3]); \
    f32x2 v0 = {s0, s0}, v1 = {s1, s1}, v2 = {s2, s2}, v3 = {s3, s3}; \
    _Pragma("unroll") \
    for (int q = 0; q < 8; ++q){ \
      f32x2 p0 = {T0[2*q], T0[2*q+1]}; \
      f32x2 p1 = {T1[2*q], T1[2*q+1]}; \
      f32x2 p2 = {T2[2*q], T2[2*q+1]}; \
      f32x2 p3 = {T3[2*q], T3[2*q+1]}; \
      asm("v_pk_fma_f32 %0, %1, %2, %0" : "+v"(accp[0][q]) : "v"(p0), "v"(v0)); \
      asm("v_pk_fma_f32 %0, %1, %2, %0" : "+v"(accp[1][q]) : "v"(p1), "v"(v1)); \
      asm("v_pk_fma_f32 %0, %1, %2, %0" : "+v"(accp[2][q]) : "v"(p2), "v"(v2)); \
      asm("v_pk_fma_f32 %0, %1, %2, %0" : "+v"(accp[3][q]) : "v"(p3), "v"(v3)); \
    } \
  } while (0)

  for (int k = 0; k < 64; k += 2){
    us4 w0 = *(const us4*)(imgP + k * 128);
    {  // prefetch k+1
      const u32x4* g = (const u32x4*)gp;
      #pragma unroll
      for (int i = 0; i < 4; ++i) avB[i] = g[i * 2 + lg];
      gp += 32768;
    }
    STEPBODY(avA, w0);

    us4 w1 = *(const us4*)(imgP + (k + 1) * 128);
    if (k + 2 < 64){
      const u32x4* g = (const u32x4*)gp;
      #pragma unroll
      for (int i = 0; i < 4; ++i) avA[i] = g[i * 2 + lg];
      gp += 32768;
    } else if (h == 0){
      const u32x4* g = (const u32x4*)biasSl;
      #pragma unroll
      for (int i = 0; i < 4; ++i) avA[i] = g[i * 2 + lg];
    }
    STEPBODY(avB, w1);
  }

  // ---- bias step (h==0): acc += A_bias x img-frags (no scale) ----
  if (h == 0){
    bf16x8 a0 = __builtin_bit_cast(bf16x8, avA[0]);
    bf16x8 a1 = __builtin_bit_cast(bf16x8, avA[1]);
    bf16x8 a2 = __builtin_bit_cast(bf16x8, avA[2]);
    bf16x8 a3 = __builtin_bit_cast(bf16x8, avA[3]);
    #pragma unroll
    for (int f = 0; f < 4; ++f){
      size_t tr = (size_t)(t0 + f * 32 + l31) * 128 + ch * 64 + lg * 8;
      f32x16 T = mfma16(a0, cvt8(&img[tr]),      Z);
      T = mfma16(a1, cvt8(&img[tr + 16]), T);
      T = mfma16(a2, cvt8(&img[tr + 32]), T);
      T = mfma16(a3, cvt8(&img[tr + 48]), T);
      #pragma unroll
      for (int q = 0; q < 8; ++q){
        accp[f][q][0] += T[2*q];
        accp[f][q][1] += T[2*q+1];
      }
    }
  }

  // ---- epilogue: combine c-halves in LDS, write partial coalesced ----
  // C/D layout: col = l31 (t), row r = (r&3) + 8*(r>>2) + 4*lg (p)
  __syncthreads();   // imgT dead; ldsY takes over
  if (ch == 0){
    #pragma unroll
    for (int f = 0; f < 4; ++f){
      int t_l = f * 32 + l31;
      #pragma unroll
      for (int r = 0; r < 16; ++r){
        int p = pt * 32 + (r & 3) + 8 * (r >> 2) + 4 * lg;
        ldsY[t_l * 129 + p] = accp[f][r >> 1][r & 1];
      }
    }
  }
  __syncthreads();
  if (ch == 1){
    #pragma unroll
    for (int f = 0; f < 4; ++f){
      int t_l = f * 32 + l31;
      #pragma unroll
      for (int r = 0; r < 16; ++r){
        int p = pt * 32 + (r & 3) + 8 * (r >> 2) + 4 * lg;
        ldsY[t_l * 129 + p] += accp[f][r >> 1][r & 1];
      }
    }
  }
  __syncthreads();
  float* dst = part + ((size_t)h * 16384 + t0) * 128;
  #pragma unroll
  for (int k = 0; k < 8; ++k){
    int idx4 = k * 512 + tid;
    int t_l = idx4 >> 5, q = idx4 & 31;
    const float* s = &ldsY[t_l * 129 + q * 4];
    float4 v = {s[0], s[1], s[2], s[3]};
    *(float4*)&dst[t_l * 128 + q * 4] = v;
  }
}

// LN kernel: y = part0 + part1, LayerNorm + ReLU. grid 256 x 512 thr.
__global__ __launch_bounds__(512)
void lnk(const float* __restrict__ part, const float* __restrict__ gamma,
         const float* __restrict__ beta, float* __restrict__ out){
  const int tid = threadIdx.x, lane = tid & 63, wv = tid >> 6;
  const float* p0 = part;
  const float* p1 = part + (size_t)16384 * 128;
  float g0  = gamma[lane], g1 = gamma[lane + 64];
  float be0 = beta[lane],  be1 = beta[lane + 64];
  int tb = blockIdx.x * 64 + wv * 8;
  #pragma unroll 1
  for (int k = 0; k < 8; ++k){
    size_t t = tb + k;
    float y0 = p0[t * 128 + lane]      + p1[t * 128 + lane];
    float y1 = p0[t * 128 + 64 + lane] + p1[t * 128 + 64 + lane];
    float s = y0 + y1, sq = y0 * y0 + y1 * y1;
    #pragma unroll
    for (int m = 32; m >= 1; m >>= 1){
      s  += __shfl_xor(s, m, 64);
      sq += __shfl_xor(sq, m, 64);
    }
    float mean = s * (1.0f / 128.0f);
    float var  = sq * (1.0f / 128.0f) - mean * mean;
    float rs   = rsqrtf(var + 1e-5f);
    float o0 = fmaxf((y0 - mean) * rs * g0 + be0, 0.0f);
    float o1 = fmaxf((y1 - mean) * rs * g1 + be1, 0.0f);
    out[t * 128 + lane]      = o0;
    out[t * 128 + 64 + lane] = o1;
  }
}

extern "C" void kernel_launch(void* const* d_in, const int* in_sizes, int n_in,
                              void* d_out, int out_size, void* d_ws, size_t ws_size,
                              hipStream_t stream){
  const float* img   = (const float*)d_in[0];
  const float* loc   = (const float*)d_in[1];
  const float* W     = (const float*)d_in[2];
  const float* bias  = (const float*)d_in[3];
  const float* gamma = (const float*)d_in[4];
  const float* beta  = (const float*)d_in[5];
  float* out = (float*)d_out;
  unsigned short* Wb3 = (unsigned short*)d_ws;                 // 4,227,072 B
  float* part = (float*)((char*)d_ws + 4227072);               // 2 x 16384 x 128 f32

  prep_wb3<<<8256, 256, 0, stream>>>(W, bias, Wb3);
  dynmlp<<<256, 512, 0, stream>>>(img, loc, Wb3, part);
  lnk<<<256, 512, 0, stream>>>(part, gamma, beta, out);
}